// Round 2
// baseline (528.013 us; speedup 1.0000x reference)
//
#include <hip/hip_runtime.h>

// GlobalFilter: y = irfft(rfft(x, n=10) * w, n=10)  ==  per-(b,d) circular conv of
// x[b,d,:] (len 10) with taps t_d derived from complex weight w_d[6]:
//
//   t_d[j] = 0.1*( Re w0 + (-1)^j Re w5
//                  + 2*sum_{k=1..4} ( Re wk * cos(2*pi*k*j/10) - Im wk * sin(2*pi*k*j/10) ) )
//   y[n]   = sum_m x[m] * t_d[(n-m) mod 10]
//
// B=8192, DIM=1024, N=10; 336 MB in + 336 MB out -> memory-bound, floor ~107 us.
//
// R2 theory: the 534 us version burned the VALU+LDS pipes on 80 scalar LDS ops/thread,
// each with a %20 + /20 magic-divide address sequence (~400 VALU instr/thread of pure
// addressing), plus ~5-way conflicts on the scatter writes. The transpose is free in
// the natural layout: write the 5 coalesced float4 linearly (lds4[t+256k], canonical
// conflict-free stride-16B), read back lds4[5t+k] (group (5t+k)%8 is a lane-residue
// permutation -> uniform 8 lanes / 4-bank group, same as linear -> conflict-free).
// 20 b128 LDS ops/thread, zero div/mod. Taps are built from w while x-loads are in
// flight. Non-temporal hints on the streaming x/y traffic (read-once/write-once).
//
// R1 fix: __builtin_nontemporal_* rejects HIP_vector_type float4* — use a clang
// ext_vector_type(4) float instead (same 16B layout, legal for the builtin).

#define BB    8192
#define DIMM  1024
#define NW    10
#define BLOCK 256
#define F4PT  5                       // float4 per thread = 2 rows = 20 floats
#define BLOCK_F4 (BLOCK * F4PT)       // 1280 float4 per block

typedef float f4 __attribute__((ext_vector_type(4)));

__global__ __launch_bounds__(BLOCK) void GlobalFilter_45784351375638_kernel(
    const float* __restrict__ x,
    const float* __restrict__ w,
    float* __restrict__ y)
{
    __shared__ f4 lds4[BLOCK_F4];              // 20 KB -> up to 8 blocks/CU

    const float c10[10] = {
        1.0f,  0.8090169943749474f,  0.30901699437494745f, -0.30901699437494745f,
        -0.8090169943749474f, -1.0f, -0.8090169943749474f, -0.30901699437494745f,
        0.30901699437494745f,  0.8090169943749474f };
    const float s10[10] = {
        0.0f,  0.5877852522924731f,  0.9510565162951535f,  0.9510565162951535f,
        0.5877852522924731f,  0.0f, -0.5877852522924731f, -0.9510565162951535f,
        -0.9510565162951535f, -0.5877852522924731f };

    const int t = threadIdx.x;
    const size_t base_f4 = (size_t)blockIdx.x * BLOCK_F4;

    // ---- issue the 5 coalesced global loads first (stay in flight during tap build)
    const f4* xg = (const f4*)x + base_f4;
    f4 v0 = __builtin_nontemporal_load(xg + t);
    f4 v1 = __builtin_nontemporal_load(xg + t + 1 * BLOCK);
    f4 v2 = __builtin_nontemporal_load(xg + t + 2 * BLOCK);
    f4 v3 = __builtin_nontemporal_load(xg + t + 3 * BLOCK);
    f4 v4 = __builtin_nontemporal_load(xg + t + 4 * BLOCK);

    // ---- weights for this thread's two rows 2T, 2T+1 (48 KB table -> L1/L2 resident)
    const int r0 = ((int)blockIdx.x * BLOCK + t) * 2;    // global row (even)
    const int d0 = r0 & (DIMM - 1);                      // even -> d0+1 never wraps
    const f4* wp = (const f4*)w + (size_t)d0 * 3;        // 12 floats = 3 f4 per row
    f4 w0 = wp[0], w1 = wp[1], w2 = wp[2], w3 = wp[3], w4 = wp[4], w5 = wp[5];
    float wf[24] = { w0.x,w0.y,w0.z,w0.w, w1.x,w1.y,w1.z,w1.w, w2.x,w2.y,w2.z,w2.w,
                     w3.x,w3.y,w3.z,w3.w, w4.x,w4.y,w4.z,w4.w, w5.x,w5.y,w5.z,w5.w };

    // ---- build the two circular-conv tap sets (overlaps x-load latency) ----
    float tt[2][NW];
#pragma unroll
    for (int rr = 0; rr < 2; ++rr) {
        const float* wd = &wf[rr * 12];        // [A0,B0, A1,B1, ..., A5,B5]
#pragma unroll
        for (int j = 0; j < NW; ++j) {
            float acc = wd[0] + ((j & 1) ? -wd[10] : wd[10]);   // Re w0 + (-1)^j Re w5
#pragma unroll
            for (int k = 1; k <= 4; ++k) {
                const int p = (k * j) % 10;                     // compile-time constant
                acc += 2.0f * (wd[2 * k] * c10[p] - wd[2 * k + 1] * s10[p]);
            }
            tt[rr][j] = 0.1f * acc;
        }
    }

    // ---- stage x through LDS: linear b128 writes, 5t+k b128 reads (both conflict-free)
    lds4[t            ] = v0;
    lds4[t + 1 * BLOCK] = v1;
    lds4[t + 2 * BLOCK] = v2;
    lds4[t + 3 * BLOCK] = v3;
    lds4[t + 4 * BLOCK] = v4;
    __syncthreads();

    float xr[2][NW];
#pragma unroll
    for (int k = 0; k < F4PT; ++k) {
        const f4 q = lds4[t * F4PT + k];
        xr[(4 * k + 0) / NW][(4 * k + 0) % NW] = q.x;   // all indices compile-time
        xr[(4 * k + 1) / NW][(4 * k + 1) % NW] = q.y;
        xr[(4 * k + 2) / NW][(4 * k + 2) % NW] = q.z;
        xr[(4 * k + 3) / NW][(4 * k + 3) % NW] = q.w;
    }

    // ---- circular convolution: 100 independent FMAs per row ----
    float out[2][NW];
#pragma unroll
    for (int rr = 0; rr < 2; ++rr) {
#pragma unroll
        for (int n = 0; n < NW; ++n) {
            float acc = 0.0f;
#pragma unroll
            for (int m = 0; m < NW; ++m) {
                acc += xr[rr][m] * tt[rr][(n - m + NW) % NW];   // compile-time index
            }
            out[rr][n] = acc;
        }
    }

    // ---- stage y through LDS: 5t+k writes, linear b128 reads -> coalesced nt stores
    __syncthreads();                            // done reading x tiles from lds
#pragma unroll
    for (int k = 0; k < F4PT; ++k) {
        f4 q;
        q.x = out[(4 * k + 0) / NW][(4 * k + 0) % NW];
        q.y = out[(4 * k + 1) / NW][(4 * k + 1) % NW];
        q.z = out[(4 * k + 2) / NW][(4 * k + 2) % NW];
        q.w = out[(4 * k + 3) / NW][(4 * k + 3) % NW];
        lds4[t * F4PT + k] = q;
    }
    __syncthreads();

    f4* yg = (f4*)y + base_f4;
    __builtin_nontemporal_store(lds4[t            ], yg + t);
    __builtin_nontemporal_store(lds4[t + 1 * BLOCK], yg + t + 1 * BLOCK);
    __builtin_nontemporal_store(lds4[t + 2 * BLOCK], yg + t + 2 * BLOCK);
    __builtin_nontemporal_store(lds4[t + 3 * BLOCK], yg + t + 3 * BLOCK);
    __builtin_nontemporal_store(lds4[t + 4 * BLOCK], yg + t + 4 * BLOCK);
}

extern "C" void kernel_launch(void* const* d_in, const int* in_sizes, int n_in,
                              void* d_out, int out_size, void* d_ws, size_t ws_size,
                              hipStream_t stream) {
    const float* x = (const float*)d_in[0];          // [8192, 1024, 10] fp32
    const float* w = (const float*)d_in[1];          // [1024, 6, 2] fp32
    float* y = (float*)d_out;                        // [8192, 1024, 10] fp32

    const int total_f4 = BB * DIMM * NW / 4;         // 20,971,520
    const int grid     = total_f4 / BLOCK_F4;        // 16,384

    GlobalFilter_45784351375638_kernel<<<grid, BLOCK, 0, stream>>>(x, w, y);
}